// Round 14
// baseline (343.392 us; speedup 1.0000x reference)
//
#include <hip/hip_runtime.h>
#include <stdint.h>
#include <stddef.h>

// Problem constants (from reference)
#define N_NODES  20000
#define N_EDGES  320000
#define N_GRAPH  64
#define F_IN     128
#define E_DIM    32
#define H_DIM    300
#define HID_DIM  600
#define DL_DIM   256
#define DOUT_DIM 128
#define BN_INV_F 0.9999950000374997f
#define EPS_MSG  1e-7f

typedef _Float16 f16;
typedef __attribute__((ext_vector_type(8))) _Float16 f16x8;
typedef __attribute__((ext_vector_type(4))) _Float16 f16x4;
typedef __attribute__((ext_vector_type(4))) float f32x4;

#define GLOAD_LDS16(gp, lp) \
    __builtin_amdgcn_global_load_lds( \
        (const __attribute__((address_space(1))) void*)(gp), \
        (__attribute__((address_space(3))) void*)(lp), 16, 0, 0)

// Bijective XCD-chunked block remap (m204): consecutive wgids land on the
// SAME XCD so y-rows sharing an A-panel reuse it in that XCD's L2.
__device__ __forceinline__ int xcd_swizzle(int bid, int nwg)
{
    int q = nwg >> 3, r = nwg & 7;
    int xcd = bid & 7, idx = bid >> 3;
    return (xcd < r ? xcd * (q + 1) : r * (q + 1) + (xcd - r) * q) + idx;
}

// ---------------------------------------------------------------------------
// Shared epilogue semantics (OUT_MODE):
//  0 f32; 1 f16 (+zero pad cols Nreal..npad); 2 split (h f16 s304 | xd f16
//  s320, pads zeroed); 3 pool-atomic (v+=bias; atomicAdd(pooled[batch[row]])).
// Grids are 1-D (nwg = gx*gy); bx/by decoded after XCD swizzle.
// ---------------------------------------------------------------------------

// 64x64 tile (validated round 10/11) — used for gemm4/gemm5.
template<bool HAS_BIAS, bool RELU, bool BN, int OUT_MODE>
__global__ __launch_bounds__(256)
void hgemm(const f16* __restrict__ A, const f16* __restrict__ Bt,
           const float* __restrict__ bias, const float* __restrict__ gamma,
           const float* __restrict__ beta,
           void* __restrict__ O1, void* __restrict__ O2,
           const int* __restrict__ batchp,
           int gx, int M, int Nreal, int Kpad, int ostride, int npad)
{
    __shared__ __align__(16) f16 As[64][32];
    __shared__ __align__(16) f16 Bs[64][32];
    const int wgid = xcd_swizzle(blockIdx.x, gridDim.x);
    const int bx   = wgid % gx;
    const int by   = wgid / gx;
    const int tid  = threadIdx.x;
    const int bm   = by * 64;
    const int bn   = bx * 64;
    const int wave = tid >> 6;
    const int lane = tid & 63;
    const int wm   = (wave >> 1) * 32;
    const int wn   = (wave & 1) * 32;
    const int fr   = lane & 15;
    const int kg   = lane >> 4;
    const int srow = tid >> 2;
    const int cg   = tid & 3;
    const int gsw  = (cg - (srow >> 1)) & 3;

    const f32x4 z = {0.f, 0.f, 0.f, 0.f};
    f32x4 acc[2][2] = {{z, z}, {z, z}};

    const f16* Asrc = A + (size_t)(bm + srow) * Kpad + gsw * 8;
    const f16* Bsrc = Bt + (size_t)(bn + srow) * Kpad + gsw * 8;
    f16* AsDst = &As[0][0] + (size_t)tid * 8;
    f16* BsDst = &Bs[0][0] + (size_t)tid * 8;

    const int ra0 = wm + fr,      ra1 = wm + 16 + fr;
    const int rb0 = wn + fr,      rb1 = wn + 16 + fr;
    const f16* a0p = &As[ra0][(((ra0 >> 1) + kg) & 3) * 8];
    const f16* a1p = &As[ra1][(((ra1 >> 1) + kg) & 3) * 8];
    const f16* b0p = &Bs[rb0][(((rb0 >> 1) + kg) & 3) * 8];
    const f16* b1p = &Bs[rb1][(((rb1 >> 1) + kg) & 3) * 8];

    for (int k0 = 0; k0 < Kpad; k0 += 32) {
        GLOAD_LDS16(Asrc, AsDst);
        GLOAD_LDS16(Bsrc, BsDst);
        Asrc += 32;
        Bsrc += 32;
        __syncthreads();
        f16x8 a0 = *(const f16x8*)a0p;
        f16x8 a1 = *(const f16x8*)a1p;
        f16x8 b0 = *(const f16x8*)b0p;
        f16x8 b1 = *(const f16x8*)b1p;
        acc[0][0] = __builtin_amdgcn_mfma_f32_16x16x32_f16(a0, b0, acc[0][0], 0, 0, 0);
        acc[0][1] = __builtin_amdgcn_mfma_f32_16x16x32_f16(a0, b1, acc[0][1], 0, 0, 0);
        acc[1][0] = __builtin_amdgcn_mfma_f32_16x16x32_f16(a1, b0, acc[1][0], 0, 0, 0);
        acc[1][1] = __builtin_amdgcn_mfma_f32_16x16x32_f16(a1, b1, acc[1][1], 0, 0, 0);
        __syncthreads();
    }

    #pragma unroll
    for (int mi = 0; mi < 2; ++mi) {
        #pragma unroll
        for (int r = 0; r < 4; ++r) {
            int row = bm + wm + mi * 16 + kg * 4 + r;
            if (row >= M) continue;
            #pragma unroll
            for (int ni = 0; ni < 2; ++ni) {
                int col = bn + wn + ni * 16 + fr;
                float v = acc[mi][ni][r];
                if (OUT_MODE == 3) {
                    if (col < Nreal) {
                        if (HAS_BIAS) v += bias[col];
                        atomicAdd(&((float*)O2)[(size_t)batchp[row] * DOUT_DIM + col], v);
                    }
                } else {
                    if (col < Nreal) {
                        if (HAS_BIAS) v += bias[col];
                        if (RELU)     v = fmaxf(v, 0.f);
                        if (BN)       v = v * (BN_INV_F * gamma[col]) + beta[col];
                        if (OUT_MODE == 0)
                            ((float*)O1)[(size_t)row * ostride + col] = v;
                        else
                            ((f16*)O1)[(size_t)row * ostride + col] = (f16)v;
                    } else if (OUT_MODE == 1 && col < npad) {
                        ((f16*)O1)[(size_t)row * ostride + col] = (f16)0.f;
                    }
                }
            }
        }
    }
}

// 64x128 tile (validated round 12): BM=64, BN=128.
template<bool HAS_BIAS, bool RELU, bool BN, int OUT_MODE>
__global__ __launch_bounds__(256)
void hgemm_n128(const f16* __restrict__ A, const f16* __restrict__ Bt,
                const float* __restrict__ bias, const float* __restrict__ gamma,
                const float* __restrict__ beta,
                void* __restrict__ O1, void* __restrict__ O2,
                int gx, int M, int Nreal, int Kpad, int ostride, int npad)
{
    __shared__ __align__(16) f16 As[64][32];
    __shared__ __align__(16) f16 Bs[128][32];
    const int wgid = xcd_swizzle(blockIdx.x, gridDim.x);
    const int bx   = wgid % gx;
    const int by   = wgid / gx;
    const int tid  = threadIdx.x;
    const int bm   = by * 64;
    const int bn   = bx * 128;
    const int wave = tid >> 6;
    const int lane = tid & 63;
    const int wm   = (wave >> 1) * 32;
    const int wn   = (wave & 1) * 64;
    const int fr   = lane & 15;
    const int kg   = lane >> 4;
    const int srow = tid >> 2;
    const int cg   = tid & 3;
    const int gsw  = (cg - (srow >> 1)) & 3;

    const f32x4 z = {0.f, 0.f, 0.f, 0.f};
    f32x4 acc[2][4];
    #pragma unroll
    for (int i = 0; i < 2; ++i)
        #pragma unroll
        for (int j = 0; j < 4; ++j)
            acc[i][j] = z;

    const f16* Asrc  = A + (size_t)(bm + srow) * Kpad + gsw * 8;
    const f16* Bsrc0 = Bt + (size_t)(bn + srow) * Kpad + gsw * 8;
    const f16* Bsrc1 = Bt + (size_t)(bn + 64 + srow) * Kpad + gsw * 8;
    f16* AsDst  = &As[0][0] + (size_t)tid * 8;
    f16* BsDst0 = &Bs[0][0] + (size_t)tid * 8;
    f16* BsDst1 = &Bs[64][0] + (size_t)tid * 8;

    const int ra0 = wm + fr, ra1 = wm + 16 + fr;
    const f16* a0p = &As[ra0][(((ra0 >> 1) + kg) & 3) * 8];
    const f16* a1p = &As[ra1][(((ra1 >> 1) + kg) & 3) * 8];
    const f16* bp0, *bp1, *bp2, *bp3;
    {
        int rb0 = wn + fr, rb1 = wn + 16 + fr, rb2 = wn + 32 + fr, rb3 = wn + 48 + fr;
        bp0 = &Bs[rb0][(((rb0 >> 1) + kg) & 3) * 8];
        bp1 = &Bs[rb1][(((rb1 >> 1) + kg) & 3) * 8];
        bp2 = &Bs[rb2][(((rb2 >> 1) + kg) & 3) * 8];
        bp3 = &Bs[rb3][(((rb3 >> 1) + kg) & 3) * 8];
    }

    for (int k0 = 0; k0 < Kpad; k0 += 32) {
        GLOAD_LDS16(Asrc, AsDst);
        GLOAD_LDS16(Bsrc0, BsDst0);
        GLOAD_LDS16(Bsrc1, BsDst1);
        Asrc += 32; Bsrc0 += 32; Bsrc1 += 32;
        __syncthreads();
        f16x8 a0 = *(const f16x8*)a0p;
        f16x8 a1 = *(const f16x8*)a1p;
        f16x8 b0 = *(const f16x8*)bp0;
        f16x8 b1 = *(const f16x8*)bp1;
        f16x8 b2 = *(const f16x8*)bp2;
        f16x8 b3 = *(const f16x8*)bp3;
        acc[0][0] = __builtin_amdgcn_mfma_f32_16x16x32_f16(a0, b0, acc[0][0], 0, 0, 0);
        acc[0][1] = __builtin_amdgcn_mfma_f32_16x16x32_f16(a0, b1, acc[0][1], 0, 0, 0);
        acc[0][2] = __builtin_amdgcn_mfma_f32_16x16x32_f16(a0, b2, acc[0][2], 0, 0, 0);
        acc[0][3] = __builtin_amdgcn_mfma_f32_16x16x32_f16(a0, b3, acc[0][3], 0, 0, 0);
        acc[1][0] = __builtin_amdgcn_mfma_f32_16x16x32_f16(a1, b0, acc[1][0], 0, 0, 0);
        acc[1][1] = __builtin_amdgcn_mfma_f32_16x16x32_f16(a1, b1, acc[1][1], 0, 0, 0);
        acc[1][2] = __builtin_amdgcn_mfma_f32_16x16x32_f16(a1, b2, acc[1][2], 0, 0, 0);
        acc[1][3] = __builtin_amdgcn_mfma_f32_16x16x32_f16(a1, b3, acc[1][3], 0, 0, 0);
        __syncthreads();
    }

    #pragma unroll
    for (int mi = 0; mi < 2; ++mi) {
        #pragma unroll
        for (int r = 0; r < 4; ++r) {
            int row = bm + wm + mi * 16 + kg * 4 + r;
            if (row >= M) continue;
            #pragma unroll
            for (int ni = 0; ni < 4; ++ni) {
                int col = bn + wn + ni * 16 + fr;
                float v = acc[mi][ni][r];
                if (OUT_MODE == 2) {
                    if (col < 300)
                        ((f16*)O1)[(size_t)row * 304 + col] = (f16)v;
                    else if (col < 600)
                        ((f16*)O2)[(size_t)row * 320 + (col - 300)] = (f16)v;
                    else if (col < 620)
                        ((f16*)O2)[(size_t)row * 320 + (col - 300)] = (f16)0.f;
                } else {
                    if (col < Nreal) {
                        if (HAS_BIAS) v += bias[col];
                        if (RELU)     v = fmaxf(v, 0.f);
                        if (BN)       v = v * (BN_INV_F * gamma[col]) + beta[col];
                        if (OUT_MODE == 0)
                            ((float*)O1)[(size_t)row * ostride + col] = v;
                        else
                            ((f16*)O1)[(size_t)row * ostride + col] = (f16)v;
                    } else if (OUT_MODE == 1 && col < npad) {
                        ((f16*)O1)[(size_t)row * ostride + col] = (f16)0.f;
                    }
                }
            }
        }
    }
}

// ---------------------------------------------------------------------------
// cast_all: x->f16, all weight transpose+casts, zero cnts + pooled.
// ---------------------------------------------------------------------------
#define XB_N   640000      // N*F/4 float4s
#define WSD_N  76800       // 600*128
#define WT1_N  192000      // 600*320
#define WT2_N  364800      // 600*608
#define WT3_N  182400      // 300*608
#define WL1_N  81920       // 256*320
#define WL2_N  32768       // 128*256
#define WET_N  9728        // 304*32
#define ZC_N   20000       // cnts
#define ZP_N   8192        // pooled
#define CAST_TOTAL (XB_N+WSD_N+WT1_N+WT2_N+WT3_N+WL1_N+WL2_N+WET_N+ZC_N+ZP_N)

__global__ __launch_bounds__(256)
void cast_all(const float* __restrict__ x,
              const float* __restrict__ Wsrc, const float* __restrict__ Wdst,
              const float* __restrict__ W1, const float* __restrict__ W2,
              const float* __restrict__ W3, const float* __restrict__ L1,
              const float* __restrict__ L2, const float* __restrict__ We,
              f16* __restrict__ xb,
              f16* __restrict__ Wt_sd, f16* __restrict__ Wt1,
              f16* __restrict__ Wt2, f16* __restrict__ Wt3,
              f16* __restrict__ WtL1, f16* __restrict__ WtL2,
              f16* __restrict__ Wet,
              int* __restrict__ cnts, float* __restrict__ pooled)
{
    int t = blockIdx.x * 256 + threadIdx.x;
    if (t < XB_N) {
        float4 v = ((const float4*)x)[t];
        f16x4 o = {(f16)v.x, (f16)v.y, (f16)v.z, (f16)v.w};
        ((f16x4*)xb)[t] = o;
        return;
    }
    t -= XB_N;
    if (t < WSD_N) {                           // rows 0..299 Wsrc, 300..599 Wdst
        int n = t / 128, k = t % 128;
        const float* W = (n < 300) ? Wsrc : Wdst;
        int nn = (n < 300) ? n : n - 300;
        Wt_sd[t] = (f16)W[(size_t)k * 300 + nn];
        return;
    }
    t -= WSD_N;
    if (t < WT1_N) {
        int n = t / 320, k = t % 320;
        Wt1[t] = (f16)((k < 300) ? W1[(size_t)k * 600 + n] : 0.f);
        return;
    }
    t -= WT1_N;
    if (t < WT2_N) {
        int n = t / 608, k = t % 608;
        Wt2[t] = (f16)((k < 600) ? W2[(size_t)k * 600 + n] : 0.f);
        return;
    }
    t -= WT2_N;
    if (t < WT3_N) {
        int n = t / 608, k = t % 608;
        Wt3[t] = (f16)((k < 600) ? W3[(size_t)k * 300 + n] : 0.f);
        return;
    }
    t -= WT3_N;
    if (t < WL1_N) {
        int n = t / 320, k = t % 320;
        WtL1[t] = (f16)((k < 300) ? L1[(size_t)k * 256 + n] : 0.f);
        return;
    }
    t -= WL1_N;
    if (t < WL2_N) {
        int n = t / 256, k = t % 256;
        WtL2[t] = (f16)L2[(size_t)k * 128 + n];
        return;
    }
    t -= WL2_N;
    if (t < WET_N) {                           // Wet[n][k] = We[k][n], rows 300..303 zero
        int n = t / 32, k = t % 32;
        Wet[t] = (f16)((n < 300) ? We[(size_t)k * 300 + n] : 0.f);
        return;
    }
    t -= WET_N;
    if (t < ZC_N) { cnts[t] = 0; return; }
    t -= ZC_N;
    if (t < ZP_N) pooled[t] = 0.f;
}

// ---------------------------------------------------------------------------
// CSR build: histogram, 2-kernel scan, fused scatter+gather.
// ---------------------------------------------------------------------------
__global__ __launch_bounds__(256)
void hist_kernel(const int* __restrict__ ei, int* __restrict__ counts)
{
    for (int e = blockIdx.x * 256 + threadIdx.x; e < N_EDGES; e += gridDim.x * 256)
        atomicAdd(&counts[ei[N_EDGES + e]], 1);
}

__global__ __launch_bounds__(256)
void scan_a(const int* __restrict__ counts, int* __restrict__ rowptr,
            int* __restrict__ bsum)
{
    __shared__ int sd[256];
    int tid = threadIdx.x;
    int i = blockIdx.x * 256 + tid;
    int v = (i < N_NODES) ? counts[i] : 0;
    sd[tid] = v;
    __syncthreads();
    #pragma unroll
    for (int off = 1; off < 256; off <<= 1) {
        int t = (tid >= off) ? sd[tid - off] : 0;
        __syncthreads();
        sd[tid] += t;
        __syncthreads();
    }
    if (i < N_NODES) rowptr[i + 1] = sd[tid];   // block-local inclusive
    if (tid == 255) bsum[blockIdx.x] = sd[255];
}

__global__ __launch_bounds__(256)
void scan_b(int* __restrict__ rowptr, int* __restrict__ shadow,
            const int* __restrict__ bsum)
{
    __shared__ int off_s;
    int tid = threadIdx.x;
    if (tid == 0) {
        int o = 0;
        for (int b = 0; b < (int)blockIdx.x; ++b) o += bsum[b];
        off_s = o;
    }
    __syncthreads();
    int i = blockIdx.x * 256 + tid;
    if (i < N_NODES) {
        int v = rowptr[i + 1] + off_s;
        rowptr[i + 1] = v;
        shadow[i + 1] = v;
    }
    if (i == 0) { rowptr[0] = 0; shadow[0] = 0; }
}

// fused scatter+gather: slot = atomicAdd(shadow[d]); write srcs/eaf directly.
__global__ __launch_bounds__(256)
void scatter_gather(const float* __restrict__ ea, const int* __restrict__ ei,
                    int* __restrict__ shadow, f16* __restrict__ eaf,
                    int* __restrict__ srcs)
{
    int e = blockIdx.x * 256 + threadIdx.x;
    if (e >= N_EDGES) return;
    int d = ei[N_EDGES + e];
    int pos = atomicAdd(&shadow[d], 1);
    srcs[pos] = ei[e];
    const float4* src = (const float4*)(ea + (size_t)e * E_DIM);
    f16* dst = eaf + (size_t)pos * E_DIM;
    #pragma unroll
    for (int q = 0; q < 8; ++q) {
        float4 v = src[q];
        f16x4 o = {(f16)v.x, (f16)v.y, (f16)v.z, (f16)v.w};
        ((f16x4*)dst)[q] = o;
    }
}

// ---------------------------------------------------------------------------
// Fused aggregation: block = 320 threads (5 waves) owns NPB=10 nodes.
// Round 14: walk does ONE branchless 32-deep load batch per chunk (was 2x16,
// which serialized: second batch's h-loads waited on first consume).
// Flush RMWs out0b (out0 = agg + xd; pad cols pre-zeroed by gemm_sd).
// ---------------------------------------------------------------------------
#define NPB 10
#define CHK 32
#define ELDS_STRIDE 308

__global__ __launch_bounds__(320, 1)
void agg_mfma(const f16* __restrict__ hf, const f16* __restrict__ eaf,
              const int* __restrict__ srcs, const int* __restrict__ rptr,
              const f16* __restrict__ Wet, f16* __restrict__ out0b)
{
    __shared__ __align__(16) f16 As[CHK][40];
    __shared__ __align__(16) f16 e_lds[CHK * ELDS_STRIDE];
    __shared__ int s_lds[CHK];

    const int tid  = threadIdx.x;
    const int w    = tid >> 6;           // wave 0..4
    const int lane = tid & 63;
    const int fr   = lane & 15;
    const int kg   = lane >> 4;
    const int c    = tid;                // channel owned in accumulate phase
    const bool act = c < H_DIM;
    const int cc   = c < 304 ? c : 303;  // clamped channel for safe loads

    const int n0 = blockIdx.x * NPB;
    const int n1 = n0 + NPB;
    const int P0 = rptr[n0];
    const int P1 = rptr[n1];

    // B-fragments: wave w owns N-tiles {w, w+5, w+10, w+15} (tile<19)
    f16x8 bf0, bf1, bf2, bf3;
    {
        int t0 = w;
        bf0 = *(const f16x8*)(Wet + (size_t)(t0 * 16 + fr) * 32 + kg * 8);
        bf1 = *(const f16x8*)(Wet + (size_t)((t0 + 5) * 16 + fr) * 32 + kg * 8);
        bf2 = *(const f16x8*)(Wet + (size_t)((t0 + 10) * 16 + fr) * 32 + kg * 8);
        if (t0 + 15 < 19)
            bf3 = *(const f16x8*)(Wet + (size_t)((t0 + 15) * 16 + fr) * 32 + kg * 8);
    }

    const f32x4 z4 = {0.f, 0.f, 0.f, 0.f};

    int n_cur = n0;
    int e_end = (n_cur < n1) ? rptr[n_cur + 1] : 0x7fffffff;
    float num = 0.f, den = 0.f;

    auto flush = [&]() {
        float agg = den > 0.f ? num / den : 0.f;
        if (act) {
            size_t idx = (size_t)n_cur * 320 + c;
            out0b[idx] = (f16)(agg + (float)out0b[idx]);   // += xd
        }
        num = 0.f; den = 0.f;
        ++n_cur;
        e_end = (n_cur < n1) ? rptr[n_cur + 1] : 0x7fffffff;
    };

    for (int ck = P0; ck < P1; ck += CHK) {
        const int cend = min(ck + CHK, P1);
        // ---- stage eaf rows + srcs for [ck, ck+32) ----
        if (tid < 128) {
            int row = tid >> 2;
            int kq  = (tid & 3) * 8;
            int p   = ck + row;
            if (p >= N_EDGES) p = N_EDGES - 1;   // clamp (garbage rows unused)
            *(f16x8*)&As[row][kq] = *(const f16x8*)(eaf + (size_t)p * E_DIM + kq);
        } else if (tid < 128 + CHK) {
            int j = tid - 128;
            int p = ck + j;
            s_lds[j] = srcs[p < N_EDGES ? p : N_EDGES - 1];
        }
        __syncthreads();
        // ---- MFMA projection: e_lds[edge][chan] = (As @ Wet^T) ----
        {
            f16x8 af0 = *(const f16x8*)&As[fr][kg * 8];
            f16x8 af1 = *(const f16x8*)&As[16 + fr][kg * 8];
            #pragma unroll
            for (int i = 0; i < 4; ++i) {
                int t = w + 5 * i;
                if (t >= 19) continue;
                f16x8 bf = (i == 0) ? bf0 : (i == 1) ? bf1 : (i == 2) ? bf2 : bf3;
                #pragma unroll
                for (int mi = 0; mi < 2; ++mi) {
                    f16x8 af = (mi == 0) ? af0 : af1;
                    f32x4 d = __builtin_amdgcn_mfma_f32_16x16x32_f16(af, bf, z4, 0, 0, 0);
                    int col = t * 16 + fr;
                    int rbase = mi * 16 + kg * 4;
                    #pragma unroll
                    for (int r = 0; r < 4; ++r)
                        e_lds[(size_t)(rbase + r) * ELDS_STRIDE + col] = (f16)d[r];
                }
            }
        }
        __syncthreads();
        // ---- walk: ONE branchless 32-deep load batch, then consume ----
        {
            float hv[CHK], ev[CHK];
            #pragma unroll
            for (int j = 0; j < CHK; ++j) {
                int s = s_lds[j];                       // always staged (clamped)
                hv[j] = (float)hf[(size_t)s * 304 + cc];
                ev[j] = (float)e_lds[(size_t)j * ELDS_STRIDE + cc];
            }
            #pragma unroll
            for (int j = 0; j < CHK; ++j) {
                int p = ck + j;
                if (p < cend) {                          // uniform guard
                    while (p == e_end) flush();
                    float msg = fmaxf(hv[j] + ev[j], 0.f) + EPS_MSG;
                    float ex = __expf(msg);
                    den += ex;
                    num += msg * ex;
                }
            }
        }
        __syncthreads();   // e_lds/As/s_lds consumed before next chunk overwrites
    }
    // flush trailing node(s) (incl. empty nodes / zero-edge blocks)
    while (n_cur < n1) flush();
}

// ---------------------------------------------------------------------------
// finalize: count per graph via binary search on sorted batch; divide.
// ---------------------------------------------------------------------------
__device__ __forceinline__ int lower_bound_batch(const int* b, int key)
{
    int lo = 0, hi = N_NODES;
    while (lo < hi) {
        int mid = (lo + hi) >> 1;
        if (b[mid] < key) lo = mid + 1; else hi = mid;
    }
    return lo;
}

__global__ __launch_bounds__(256)
void finalize_kernel(const float* __restrict__ pooled, const int* __restrict__ batch,
                     float* __restrict__ out)
{
    int i = blockIdx.x * 256 + threadIdx.x;
    if (i >= N_GRAPH * DOUT_DIM) return;
    int g = i / DOUT_DIM;
    int cnt = lower_bound_batch(batch, g + 1) - lower_bound_batch(batch, g);
    out[i] = pooled[i] / fmaxf((float)cnt, 1.f);
}

// ---------------------------------------------------------------------------
extern "C" void kernel_launch(void* const* d_in, const int* in_sizes, int n_in,
                              void* d_out, int out_size, void* d_ws, size_t ws_size,
                              hipStream_t stream)
{
    const float* x      = (const float*)d_in[0];
    const float* ea     = (const float*)d_in[1];
    const int*   eidx   = (const int*)d_in[2];
    const int*   batch  = (const int*)d_in[3];
    const float* W_src  = (const float*)d_in[4];
    const float* W_edge = (const float*)d_in[5];
    const float* W_dst  = (const float*)d_in[6];
    const float* W1     = (const float*)d_in[7];
    const float* b1     = (const float*)d_in[8];
    const float* g1     = (const float*)d_in[9];
    const float* be1    = (const float*)d_in[10];
    const float* W2     = (const float*)d_in[11];
    const float* b2     = (const float*)d_in[12];
    const float* g2     = (const float*)d_in[13];
    const float* be2    = (const float*)d_in[14];
    const float* W3     = (const float*)d_in[15];
    const float* b3     = (const float*)d_in[16];
    const float* L1     = (const float*)d_in[17];
    const float* bl1    = (const float*)d_in[18];
    const float* L2     = (const float*)d_in[19];
    const float* bl2    = (const float*)d_in[20];
    float* out = (float*)d_out;
    char* ws = (char*)d_ws;

    // Clean overlay (peak 78.3 MB, all live ranges disjoint)
    f16*   ws_h     = (f16*)  (ws + 0);
    f16*   ws_xb    = (f16*)  (ws + 12160000);
    f16*   ws_eaf   = (f16*)  (ws + 17280000);
    int*   ws_srcs  = (int*)  (ws + 37760000);
    f16*   ws_out0b = (f16*)  (ws + 39040000);
    f16*   ws_b1b   = (f16*)  (ws + 51840000);
    f16*   ws_b2b   = (f16*)  (ws + 0);
    f16*   ws_out1b = (f16*)  (ws + 24320000);
    f16*   ws_out2b = (f16*)  (ws + 37120000);
    f16*   ws_wtsd  = (f16*)  (ws + 76160000);
    f16*   ws_wt1   = (f16*)  (ws + 76313600);
    f16*   ws_wt2   = (f16*)  (ws + 76697600);
    f16*   ws_wt3   = (f16*)  (ws + 77427200);
    f16*   ws_wtl1  = (f16*)  (ws + 77792000);
    f16*   ws_wtl2  = (f16*)  (ws + 77955840);
    f16*   ws_wet   = (f16*)  (ws + 78021376);
    int*   ws_cnts  = (int*)  (ws + 78040832);   // [20000]
    int*   ws_rptr  = (int*)  (ws + 78120832);   // [20001]
    int*   ws_shad  = (int*)  (ws + 78200848);   // [20001]
    int*   ws_bsum  = (int*)  (ws + 78280864);   // [79]
    float* ws_pool  = (float*)(ws + 78281248);   // [64,128]

    dim3 blk(256);

    // casts + zero-init (cnts, pooled)
    cast_all<<<(CAST_TOTAL + 255) / 256, blk, 0, stream>>>(
        x, W_src, W_dst, W1, W2, W3, L1, L2, W_edge,
        ws_xb, ws_wtsd, ws_wt1, ws_wt2, ws_wt3, ws_wtl1, ws_wtl2, ws_wet,
        ws_cnts, ws_pool);

    // h | xd  = x @ [W_src ; W_dst]   (h f16 s304; xd -> out0b f16 s320, pads 0)
    hgemm_n128<false, false, false, 2><<<dim3(5 * 313), blk, 0, stream>>>(
        ws_xb, ws_wtsd, nullptr, nullptr, nullptr, ws_h, ws_out0b,
        5, N_NODES, 600, 128, 304, 608);

    // CSR build + fused scatter/gather
    hist_kernel<<<512, blk, 0, stream>>>(eidx, ws_cnts);
    {
        int nb = (N_NODES + 255) / 256;   // 79
        scan_a<<<nb, blk, 0, stream>>>(ws_cnts, ws_rptr, ws_bsum);
        scan_b<<<nb, blk, 0, stream>>>(ws_rptr, ws_shad, ws_bsum);
    }
    scatter_gather<<<(N_EDGES + 255) / 256, blk, 0, stream>>>(
        ea, eidx, ws_shad, ws_eaf, ws_srcs);

    // fused MFMA aggregation (out0b = agg + xd, RMW)
    agg_mfma<<<N_NODES / NPB, dim3(320), 0, stream>>>(
        ws_h, ws_eaf, ws_srcs, ws_rptr, ws_wet, ws_out0b);

    // MLP + encoder chain (f16 MFMA, fp32 accum), XCD-chunked block order
    hgemm_n128<true, true, true, 1><<<dim3(5 * 313), blk, 0, stream>>>(
        ws_out0b, ws_wt1, b1, g1, be1, ws_b1b, nullptr,
        5, N_NODES, 600, 320, 608, 608);
    hgemm_n128<true, true, true, 1><<<dim3(5 * 313), blk, 0, stream>>>(
        ws_b1b, ws_wt2, b2, g2, be2, ws_b2b, nullptr,
        5, N_NODES, 600, 608, 608, 608);
    hgemm_n128<true, false, false, 1><<<dim3(3 * 313), blk, 0, stream>>>(
        ws_b2b, ws_wt3, b3, nullptr, nullptr, ws_out1b, nullptr,
        3, N_NODES, 300, 608, 320, 320);
    hgemm<true, true, false, 1><<<dim3(4 * 313), blk, 0, stream>>>(
        ws_out1b, ws_wtl1, bl1, nullptr, nullptr, ws_out2b, nullptr, nullptr,
        4, N_NODES, 256, 320, 256, 256);
    // gemm5: epilogue pools directly (atomicAdd into pooled[batch[row]])
    hgemm<true, false, false, 3><<<dim3(2 * 313), blk, 0, stream>>>(
        ws_out2b, ws_wtl2, bl2, nullptr, nullptr, nullptr, ws_pool, batch,
        2, N_NODES, 128, 256, 128, 128);

    // finalize: per-graph mean via binary search on sorted batch
    finalize_kernel<<<(N_GRAPH * DOUT_DIM + 255) / 256, blk, 0, stream>>>(
        ws_pool, batch, out);
}

// Round 15
// 315.173 us; speedup vs baseline: 1.0895x; 1.0895x over previous
//
#include <hip/hip_runtime.h>
#include <stdint.h>
#include <stddef.h>

// Problem constants (from reference)
#define N_NODES  20000
#define N_EDGES  320000
#define N_GRAPH  64
#define F_IN     128
#define E_DIM    32
#define H_DIM    300
#define HID_DIM  600
#define DL_DIM   256
#define DOUT_DIM 128
#define BN_INV_F 0.9999950000374997f
#define EPS_MSG  1e-7f

typedef _Float16 f16;
typedef __attribute__((ext_vector_type(8))) _Float16 f16x8;
typedef __attribute__((ext_vector_type(4))) _Float16 f16x4;
typedef __attribute__((ext_vector_type(4))) float f32x4;

#define GLOAD_LDS16(gp, lp) \
    __builtin_amdgcn_global_load_lds( \
        (const __attribute__((address_space(1))) void*)(gp), \
        (__attribute__((address_space(3))) void*)(lp), 16, 0, 0)

// Bijective XCD-chunked block remap (m204): consecutive wgids land on the
// SAME XCD so y-rows sharing an A-panel reuse it in that XCD's L2.
__device__ __forceinline__ int xcd_swizzle(int bid, int nwg)
{
    int q = nwg >> 3, r = nwg & 7;
    int xcd = bid & 7, idx = bid >> 3;
    return (xcd < r ? xcd * (q + 1) : r * (q + 1) + (xcd - r) * q) + idx;
}

// ---------------------------------------------------------------------------
// Shared epilogue semantics (OUT_MODE):
//  0 f32; 1 f16 (+zero pad cols Nreal..npad); 2 split (h f16 s304 | xd f16
//  s320, pads zeroed); 3 pool-atomic (v+=bias; atomicAdd(pooled[batch[row]])).
// Grids are 1-D (nwg = gx*gy); bx/by decoded after XCD swizzle.
// ---------------------------------------------------------------------------

// 64x64 tile (validated round 10/11) — used for gemm4/gemm5.
template<bool HAS_BIAS, bool RELU, bool BN, int OUT_MODE>
__global__ __launch_bounds__(256)
void hgemm(const f16* __restrict__ A, const f16* __restrict__ Bt,
           const float* __restrict__ bias, const float* __restrict__ gamma,
           const float* __restrict__ beta,
           void* __restrict__ O1, void* __restrict__ O2,
           const int* __restrict__ batchp,
           int gx, int M, int Nreal, int Kpad, int ostride, int npad)
{
    __shared__ __align__(16) f16 As[64][32];
    __shared__ __align__(16) f16 Bs[64][32];
    const int wgid = xcd_swizzle(blockIdx.x, gridDim.x);
    const int bx   = wgid % gx;
    const int by   = wgid / gx;
    const int tid  = threadIdx.x;
    const int bm   = by * 64;
    const int bn   = bx * 64;
    const int wave = tid >> 6;
    const int lane = tid & 63;
    const int wm   = (wave >> 1) * 32;
    const int wn   = (wave & 1) * 32;
    const int fr   = lane & 15;
    const int kg   = lane >> 4;
    const int srow = tid >> 2;
    const int cg   = tid & 3;
    const int gsw  = (cg - (srow >> 1)) & 3;

    const f32x4 z = {0.f, 0.f, 0.f, 0.f};
    f32x4 acc[2][2] = {{z, z}, {z, z}};

    const f16* Asrc = A + (size_t)(bm + srow) * Kpad + gsw * 8;
    const f16* Bsrc = Bt + (size_t)(bn + srow) * Kpad + gsw * 8;
    f16* AsDst = &As[0][0] + (size_t)tid * 8;
    f16* BsDst = &Bs[0][0] + (size_t)tid * 8;

    const int ra0 = wm + fr,      ra1 = wm + 16 + fr;
    const int rb0 = wn + fr,      rb1 = wn + 16 + fr;
    const f16* a0p = &As[ra0][(((ra0 >> 1) + kg) & 3) * 8];
    const f16* a1p = &As[ra1][(((ra1 >> 1) + kg) & 3) * 8];
    const f16* b0p = &Bs[rb0][(((rb0 >> 1) + kg) & 3) * 8];
    const f16* b1p = &Bs[rb1][(((rb1 >> 1) + kg) & 3) * 8];

    for (int k0 = 0; k0 < Kpad; k0 += 32) {
        GLOAD_LDS16(Asrc, AsDst);
        GLOAD_LDS16(Bsrc, BsDst);
        Asrc += 32;
        Bsrc += 32;
        __syncthreads();
        f16x8 a0 = *(const f16x8*)a0p;
        f16x8 a1 = *(const f16x8*)a1p;
        f16x8 b0 = *(const f16x8*)b0p;
        f16x8 b1 = *(const f16x8*)b1p;
        acc[0][0] = __builtin_amdgcn_mfma_f32_16x16x32_f16(a0, b0, acc[0][0], 0, 0, 0);
        acc[0][1] = __builtin_amdgcn_mfma_f32_16x16x32_f16(a0, b1, acc[0][1], 0, 0, 0);
        acc[1][0] = __builtin_amdgcn_mfma_f32_16x16x32_f16(a1, b0, acc[1][0], 0, 0, 0);
        acc[1][1] = __builtin_amdgcn_mfma_f32_16x16x32_f16(a1, b1, acc[1][1], 0, 0, 0);
        __syncthreads();
    }

    #pragma unroll
    for (int mi = 0; mi < 2; ++mi) {
        #pragma unroll
        for (int r = 0; r < 4; ++r) {
            int row = bm + wm + mi * 16 + kg * 4 + r;
            if (row >= M) continue;
            #pragma unroll
            for (int ni = 0; ni < 2; ++ni) {
                int col = bn + wn + ni * 16 + fr;
                float v = acc[mi][ni][r];
                if (OUT_MODE == 3) {
                    if (col < Nreal) {
                        if (HAS_BIAS) v += bias[col];
                        atomicAdd(&((float*)O2)[(size_t)batchp[row] * DOUT_DIM + col], v);
                    }
                } else {
                    if (col < Nreal) {
                        if (HAS_BIAS) v += bias[col];
                        if (RELU)     v = fmaxf(v, 0.f);
                        if (BN)       v = v * (BN_INV_F * gamma[col]) + beta[col];
                        if (OUT_MODE == 0)
                            ((float*)O1)[(size_t)row * ostride + col] = v;
                        else
                            ((f16*)O1)[(size_t)row * ostride + col] = (f16)v;
                    } else if (OUT_MODE == 1 && col < npad) {
                        ((f16*)O1)[(size_t)row * ostride + col] = (f16)0.f;
                    }
                }
            }
        }
    }
}

// 64x128 tile (validated round 12): BM=64, BN=128.
template<bool HAS_BIAS, bool RELU, bool BN, int OUT_MODE>
__global__ __launch_bounds__(256)
void hgemm_n128(const f16* __restrict__ A, const f16* __restrict__ Bt,
                const float* __restrict__ bias, const float* __restrict__ gamma,
                const float* __restrict__ beta,
                void* __restrict__ O1, void* __restrict__ O2,
                int gx, int M, int Nreal, int Kpad, int ostride, int npad)
{
    __shared__ __align__(16) f16 As[64][32];
    __shared__ __align__(16) f16 Bs[128][32];
    const int wgid = xcd_swizzle(blockIdx.x, gridDim.x);
    const int bx   = wgid % gx;
    const int by   = wgid / gx;
    const int tid  = threadIdx.x;
    const int bm   = by * 64;
    const int bn   = bx * 128;
    const int wave = tid >> 6;
    const int lane = tid & 63;
    const int wm   = (wave >> 1) * 32;
    const int wn   = (wave & 1) * 64;
    const int fr   = lane & 15;
    const int kg   = lane >> 4;
    const int srow = tid >> 2;
    const int cg   = tid & 3;
    const int gsw  = (cg - (srow >> 1)) & 3;

    const f32x4 z = {0.f, 0.f, 0.f, 0.f};
    f32x4 acc[2][4];
    #pragma unroll
    for (int i = 0; i < 2; ++i)
        #pragma unroll
        for (int j = 0; j < 4; ++j)
            acc[i][j] = z;

    const f16* Asrc  = A + (size_t)(bm + srow) * Kpad + gsw * 8;
    const f16* Bsrc0 = Bt + (size_t)(bn + srow) * Kpad + gsw * 8;
    const f16* Bsrc1 = Bt + (size_t)(bn + 64 + srow) * Kpad + gsw * 8;
    f16* AsDst  = &As[0][0] + (size_t)tid * 8;
    f16* BsDst0 = &Bs[0][0] + (size_t)tid * 8;
    f16* BsDst1 = &Bs[64][0] + (size_t)tid * 8;

    const int ra0 = wm + fr, ra1 = wm + 16 + fr;
    const f16* a0p = &As[ra0][(((ra0 >> 1) + kg) & 3) * 8];
    const f16* a1p = &As[ra1][(((ra1 >> 1) + kg) & 3) * 8];
    const f16* bp0, *bp1, *bp2, *bp3;
    {
        int rb0 = wn + fr, rb1 = wn + 16 + fr, rb2 = wn + 32 + fr, rb3 = wn + 48 + fr;
        bp0 = &Bs[rb0][(((rb0 >> 1) + kg) & 3) * 8];
        bp1 = &Bs[rb1][(((rb1 >> 1) + kg) & 3) * 8];
        bp2 = &Bs[rb2][(((rb2 >> 1) + kg) & 3) * 8];
        bp3 = &Bs[rb3][(((rb3 >> 1) + kg) & 3) * 8];
    }

    for (int k0 = 0; k0 < Kpad; k0 += 32) {
        GLOAD_LDS16(Asrc, AsDst);
        GLOAD_LDS16(Bsrc0, BsDst0);
        GLOAD_LDS16(Bsrc1, BsDst1);
        Asrc += 32; Bsrc0 += 32; Bsrc1 += 32;
        __syncthreads();
        f16x8 a0 = *(const f16x8*)a0p;
        f16x8 a1 = *(const f16x8*)a1p;
        f16x8 b0 = *(const f16x8*)bp0;
        f16x8 b1 = *(const f16x8*)bp1;
        f16x8 b2 = *(const f16x8*)bp2;
        f16x8 b3 = *(const f16x8*)bp3;
        acc[0][0] = __builtin_amdgcn_mfma_f32_16x16x32_f16(a0, b0, acc[0][0], 0, 0, 0);
        acc[0][1] = __builtin_amdgcn_mfma_f32_16x16x32_f16(a0, b1, acc[0][1], 0, 0, 0);
        acc[0][2] = __builtin_amdgcn_mfma_f32_16x16x32_f16(a0, b2, acc[0][2], 0, 0, 0);
        acc[0][3] = __builtin_amdgcn_mfma_f32_16x16x32_f16(a0, b3, acc[0][3], 0, 0, 0);
        acc[1][0] = __builtin_amdgcn_mfma_f32_16x16x32_f16(a1, b0, acc[1][0], 0, 0, 0);
        acc[1][1] = __builtin_amdgcn_mfma_f32_16x16x32_f16(a1, b1, acc[1][1], 0, 0, 0);
        acc[1][2] = __builtin_amdgcn_mfma_f32_16x16x32_f16(a1, b2, acc[1][2], 0, 0, 0);
        acc[1][3] = __builtin_amdgcn_mfma_f32_16x16x32_f16(a1, b3, acc[1][3], 0, 0, 0);
        __syncthreads();
    }

    #pragma unroll
    for (int mi = 0; mi < 2; ++mi) {
        #pragma unroll
        for (int r = 0; r < 4; ++r) {
            int row = bm + wm + mi * 16 + kg * 4 + r;
            if (row >= M) continue;
            #pragma unroll
            for (int ni = 0; ni < 4; ++ni) {
                int col = bn + wn + ni * 16 + fr;
                float v = acc[mi][ni][r];
                if (OUT_MODE == 2) {
                    if (col < 300)
                        ((f16*)O1)[(size_t)row * 304 + col] = (f16)v;
                    else if (col < 600)
                        ((f16*)O2)[(size_t)row * 320 + (col - 300)] = (f16)v;
                    else if (col < 620)
                        ((f16*)O2)[(size_t)row * 320 + (col - 300)] = (f16)0.f;
                } else {
                    if (col < Nreal) {
                        if (HAS_BIAS) v += bias[col];
                        if (RELU)     v = fmaxf(v, 0.f);
                        if (BN)       v = v * (BN_INV_F * gamma[col]) + beta[col];
                        if (OUT_MODE == 0)
                            ((float*)O1)[(size_t)row * ostride + col] = v;
                        else
                            ((f16*)O1)[(size_t)row * ostride + col] = (f16)v;
                    } else if (OUT_MODE == 1 && col < npad) {
                        ((f16*)O1)[(size_t)row * ostride + col] = (f16)0.f;
                    }
                }
            }
        }
    }
}

// ---------------------------------------------------------------------------
// cast_all: x->f16, all weight transpose+casts, zero cnts + pooled.
// ---------------------------------------------------------------------------
#define XB_N   640000      // N*F/4 float4s
#define WSD_N  76800       // 600*128
#define WT1_N  192000      // 600*320
#define WT2_N  364800      // 600*608
#define WT3_N  182400      // 300*608
#define WL1_N  81920       // 256*320
#define WL2_N  32768       // 128*256
#define WET_N  9728        // 304*32
#define ZC_N   20000       // cnts
#define ZP_N   8192        // pooled
#define CAST_TOTAL (XB_N+WSD_N+WT1_N+WT2_N+WT3_N+WL1_N+WL2_N+WET_N+ZC_N+ZP_N)

__global__ __launch_bounds__(256)
void cast_all(const float* __restrict__ x,
              const float* __restrict__ Wsrc, const float* __restrict__ Wdst,
              const float* __restrict__ W1, const float* __restrict__ W2,
              const float* __restrict__ W3, const float* __restrict__ L1,
              const float* __restrict__ L2, const float* __restrict__ We,
              f16* __restrict__ xb,
              f16* __restrict__ Wt_sd, f16* __restrict__ Wt1,
              f16* __restrict__ Wt2, f16* __restrict__ Wt3,
              f16* __restrict__ WtL1, f16* __restrict__ WtL2,
              f16* __restrict__ Wet,
              int* __restrict__ cnts, float* __restrict__ pooled)
{
    int t = blockIdx.x * 256 + threadIdx.x;
    if (t < XB_N) {
        float4 v = ((const float4*)x)[t];
        f16x4 o = {(f16)v.x, (f16)v.y, (f16)v.z, (f16)v.w};
        ((f16x4*)xb)[t] = o;
        return;
    }
    t -= XB_N;
    if (t < WSD_N) {                           // rows 0..299 Wsrc, 300..599 Wdst
        int n = t / 128, k = t % 128;
        const float* W = (n < 300) ? Wsrc : Wdst;
        int nn = (n < 300) ? n : n - 300;
        Wt_sd[t] = (f16)W[(size_t)k * 300 + nn];
        return;
    }
    t -= WSD_N;
    if (t < WT1_N) {
        int n = t / 320, k = t % 320;
        Wt1[t] = (f16)((k < 300) ? W1[(size_t)k * 600 + n] : 0.f);
        return;
    }
    t -= WT1_N;
    if (t < WT2_N) {
        int n = t / 608, k = t % 608;
        Wt2[t] = (f16)((k < 600) ? W2[(size_t)k * 600 + n] : 0.f);
        return;
    }
    t -= WT2_N;
    if (t < WT3_N) {
        int n = t / 608, k = t % 608;
        Wt3[t] = (f16)((k < 600) ? W3[(size_t)k * 300 + n] : 0.f);
        return;
    }
    t -= WT3_N;
    if (t < WL1_N) {
        int n = t / 320, k = t % 320;
        WtL1[t] = (f16)((k < 300) ? L1[(size_t)k * 256 + n] : 0.f);
        return;
    }
    t -= WL1_N;
    if (t < WL2_N) {
        int n = t / 256, k = t % 256;
        WtL2[t] = (f16)L2[(size_t)k * 128 + n];
        return;
    }
    t -= WL2_N;
    if (t < WET_N) {                           // Wet[n][k] = We[k][n], rows 300..303 zero
        int n = t / 32, k = t % 32;
        Wet[t] = (f16)((n < 300) ? We[(size_t)k * 300 + n] : 0.f);
        return;
    }
    t -= WET_N;
    if (t < ZC_N) { cnts[t] = 0; return; }
    t -= ZC_N;
    if (t < ZP_N) pooled[t] = 0.f;
}

// ---------------------------------------------------------------------------
// CSR build: histogram, 2-kernel scan, fused scatter+gather.
// ---------------------------------------------------------------------------
__global__ __launch_bounds__(256)
void hist_kernel(const int* __restrict__ ei, int* __restrict__ counts)
{
    for (int e = blockIdx.x * 256 + threadIdx.x; e < N_EDGES; e += gridDim.x * 256)
        atomicAdd(&counts[ei[N_EDGES + e]], 1);
}

__global__ __launch_bounds__(256)
void scan_a(const int* __restrict__ counts, int* __restrict__ rowptr,
            int* __restrict__ bsum)
{
    __shared__ int sd[256];
    int tid = threadIdx.x;
    int i = blockIdx.x * 256 + tid;
    int v = (i < N_NODES) ? counts[i] : 0;
    sd[tid] = v;
    __syncthreads();
    #pragma unroll
    for (int off = 1; off < 256; off <<= 1) {
        int t = (tid >= off) ? sd[tid - off] : 0;
        __syncthreads();
        sd[tid] += t;
        __syncthreads();
    }
    if (i < N_NODES) rowptr[i + 1] = sd[tid];   // block-local inclusive
    if (tid == 255) bsum[blockIdx.x] = sd[255];
}

__global__ __launch_bounds__(256)
void scan_b(int* __restrict__ rowptr, int* __restrict__ shadow,
            const int* __restrict__ bsum)
{
    __shared__ int off_s;
    int tid = threadIdx.x;
    if (tid == 0) {
        int o = 0;
        for (int b = 0; b < (int)blockIdx.x; ++b) o += bsum[b];
        off_s = o;
    }
    __syncthreads();
    int i = blockIdx.x * 256 + tid;
    if (i < N_NODES) {
        int v = rowptr[i + 1] + off_s;
        rowptr[i + 1] = v;
        shadow[i + 1] = v;
    }
    if (i == 0) { rowptr[0] = 0; shadow[0] = 0; }
}

// fused scatter+gather: slot = atomicAdd(shadow[d]); write srcs/eaf directly.
__global__ __launch_bounds__(256)
void scatter_gather(const float* __restrict__ ea, const int* __restrict__ ei,
                    int* __restrict__ shadow, f16* __restrict__ eaf,
                    int* __restrict__ srcs)
{
    int e = blockIdx.x * 256 + threadIdx.x;
    if (e >= N_EDGES) return;
    int d = ei[N_EDGES + e];
    int pos = atomicAdd(&shadow[d], 1);
    srcs[pos] = ei[e];
    const float4* src = (const float4*)(ea + (size_t)e * E_DIM);
    f16* dst = eaf + (size_t)pos * E_DIM;
    #pragma unroll
    for (int q = 0; q < 8; ++q) {
        float4 v = src[q];
        f16x4 o = {(f16)v.x, (f16)v.y, (f16)v.z, (f16)v.w};
        ((f16x4*)dst)[q] = o;
    }
}

// ---------------------------------------------------------------------------
// Fused aggregation (validated round 7/11/13): block = 320 threads (5 waves)
// owns NPB=10 nodes. Branchless 16-deep register prefetch (round 14's 32-deep
// variant regressed: VGPR 40->60 cut occupancy 37->21%, TLP loss > ILP gain).
// Flush RMWs out0b (out0 = agg + xd; pad cols pre-zeroed by gemm_sd).
// ---------------------------------------------------------------------------
#define NPB 10
#define CHK 32
#define ELDS_STRIDE 308

__global__ __launch_bounds__(320, 1)
void agg_mfma(const f16* __restrict__ hf, const f16* __restrict__ eaf,
              const int* __restrict__ srcs, const int* __restrict__ rptr,
              const f16* __restrict__ Wet, f16* __restrict__ out0b)
{
    __shared__ __align__(16) f16 As[CHK][40];
    __shared__ __align__(16) f16 e_lds[CHK * ELDS_STRIDE];
    __shared__ int s_lds[CHK];

    const int tid  = threadIdx.x;
    const int w    = tid >> 6;           // wave 0..4
    const int lane = tid & 63;
    const int fr   = lane & 15;
    const int kg   = lane >> 4;
    const int c    = tid;                // channel owned in accumulate phase
    const bool act = c < H_DIM;
    const int cc   = c < 304 ? c : 303;  // clamped channel for safe loads

    const int n0 = blockIdx.x * NPB;
    const int n1 = n0 + NPB;
    const int P0 = rptr[n0];
    const int P1 = rptr[n1];

    // B-fragments: wave w owns N-tiles {w, w+5, w+10, w+15} (tile<19)
    f16x8 bf0, bf1, bf2, bf3;
    {
        int t0 = w;
        bf0 = *(const f16x8*)(Wet + (size_t)(t0 * 16 + fr) * 32 + kg * 8);
        bf1 = *(const f16x8*)(Wet + (size_t)((t0 + 5) * 16 + fr) * 32 + kg * 8);
        bf2 = *(const f16x8*)(Wet + (size_t)((t0 + 10) * 16 + fr) * 32 + kg * 8);
        if (t0 + 15 < 19)
            bf3 = *(const f16x8*)(Wet + (size_t)((t0 + 15) * 16 + fr) * 32 + kg * 8);
    }

    const f32x4 z4 = {0.f, 0.f, 0.f, 0.f};

    int n_cur = n0;
    int e_end = (n_cur < n1) ? rptr[n_cur + 1] : 0x7fffffff;
    float num = 0.f, den = 0.f;

    auto flush = [&]() {
        float agg = den > 0.f ? num / den : 0.f;
        if (act) {
            size_t idx = (size_t)n_cur * 320 + c;
            out0b[idx] = (f16)(agg + (float)out0b[idx]);   // += xd
        }
        num = 0.f; den = 0.f;
        ++n_cur;
        e_end = (n_cur < n1) ? rptr[n_cur + 1] : 0x7fffffff;
    };

    for (int ck = P0; ck < P1; ck += CHK) {
        const int cend = min(ck + CHK, P1);
        // ---- stage eaf rows + srcs for [ck, ck+32) ----
        if (tid < 128) {
            int row = tid >> 2;
            int kq  = (tid & 3) * 8;
            int p   = ck + row;
            if (p >= N_EDGES) p = N_EDGES - 1;   // clamp (garbage rows unused)
            *(f16x8*)&As[row][kq] = *(const f16x8*)(eaf + (size_t)p * E_DIM + kq);
        } else if (tid < 128 + CHK) {
            int j = tid - 128;
            int p = ck + j;
            s_lds[j] = srcs[p < N_EDGES ? p : N_EDGES - 1];
        }
        __syncthreads();
        // ---- MFMA projection: e_lds[edge][chan] = (As @ Wet^T) ----
        {
            f16x8 af0 = *(const f16x8*)&As[fr][kg * 8];
            f16x8 af1 = *(const f16x8*)&As[16 + fr][kg * 8];
            #pragma unroll
            for (int i = 0; i < 4; ++i) {
                int t = w + 5 * i;
                if (t >= 19) continue;
                f16x8 bf = (i == 0) ? bf0 : (i == 1) ? bf1 : (i == 2) ? bf2 : bf3;
                #pragma unroll
                for (int mi = 0; mi < 2; ++mi) {
                    f16x8 af = (mi == 0) ? af0 : af1;
                    f32x4 d = __builtin_amdgcn_mfma_f32_16x16x32_f16(af, bf, z4, 0, 0, 0);
                    int col = t * 16 + fr;
                    int rbase = mi * 16 + kg * 4;
                    #pragma unroll
                    for (int r = 0; r < 4; ++r)
                        e_lds[(size_t)(rbase + r) * ELDS_STRIDE + col] = (f16)d[r];
                }
            }
        }
        __syncthreads();
        // ---- walk: branchless 16-deep register prefetch, then consume ----
        for (int ck2 = ck; ck2 < cend; ck2 += 16) {
            float hv[16], ev[16];
            #pragma unroll
            for (int j = 0; j < 16; ++j) {
                int idx = (ck2 - ck) + j;               // 0..31, always staged
                int s = s_lds[idx];
                hv[j] = (float)hf[(size_t)s * 304 + cc];
                ev[j] = (float)e_lds[(size_t)idx * ELDS_STRIDE + cc];
            }
            #pragma unroll
            for (int j = 0; j < 16; ++j) {
                int p = ck2 + j;
                if (p < cend) {                          // uniform guard
                    while (p == e_end) flush();
                    float msg = fmaxf(hv[j] + ev[j], 0.f) + EPS_MSG;
                    float ex = __expf(msg);
                    den += ex;
                    num += msg * ex;
                }
            }
        }
        __syncthreads();   // e_lds/As/s_lds consumed before next chunk overwrites
    }
    // flush trailing node(s) (incl. empty nodes / zero-edge blocks)
    while (n_cur < n1) flush();
}

// ---------------------------------------------------------------------------
// finalize: count per graph via binary search on sorted batch; divide.
// ---------------------------------------------------------------------------
__device__ __forceinline__ int lower_bound_batch(const int* b, int key)
{
    int lo = 0, hi = N_NODES;
    while (lo < hi) {
        int mid = (lo + hi) >> 1;
        if (b[mid] < key) lo = mid + 1; else hi = mid;
    }
    return lo;
}

__global__ __launch_bounds__(256)
void finalize_kernel(const float* __restrict__ pooled, const int* __restrict__ batch,
                     float* __restrict__ out)
{
    int i = blockIdx.x * 256 + threadIdx.x;
    if (i >= N_GRAPH * DOUT_DIM) return;
    int g = i / DOUT_DIM;
    int cnt = lower_bound_batch(batch, g + 1) - lower_bound_batch(batch, g);
    out[i] = pooled[i] / fmaxf((float)cnt, 1.f);
}

// ---------------------------------------------------------------------------
extern "C" void kernel_launch(void* const* d_in, const int* in_sizes, int n_in,
                              void* d_out, int out_size, void* d_ws, size_t ws_size,
                              hipStream_t stream)
{
    const float* x      = (const float*)d_in[0];
    const float* ea     = (const float*)d_in[1];
    const int*   eidx   = (const int*)d_in[2];
    const int*   batch  = (const int*)d_in[3];
    const float* W_src  = (const float*)d_in[4];
    const float* W_edge = (const float*)d_in[5];
    const float* W_dst  = (const float*)d_in[6];
    const float* W1     = (const float*)d_in[7];
    const float* b1     = (const float*)d_in[8];
    const float* g1     = (const float*)d_in[9];
    const float* be1    = (const float*)d_in[10];
    const float* W2     = (const float*)d_in[11];
    const float* b2     = (const float*)d_in[12];
    const float* g2     = (const float*)d_in[13];
    const float* be2    = (const float*)d_in[14];
    const float* W3     = (const float*)d_in[15];
    const float* b3     = (const float*)d_in[16];
    const float* L1     = (const float*)d_in[17];
    const float* bl1    = (const float*)d_in[18];
    const float* L2     = (const float*)d_in[19];
    const float* bl2    = (const float*)d_in[20];
    float* out = (float*)d_out;
    char* ws = (char*)d_ws;

    // Clean overlay (peak 78.3 MB, all live ranges disjoint)
    f16*   ws_h     = (f16*)  (ws + 0);
    f16*   ws_xb    = (f16*)  (ws + 12160000);
    f16*   ws_eaf   = (f16*)  (ws + 17280000);
    int*   ws_srcs  = (int*)  (ws + 37760000);
    f16*   ws_out0b = (f16*)  (ws + 39040000);
    f16*   ws_b1b   = (f16*)  (ws + 51840000);
    f16*   ws_b2b   = (f16*)  (ws + 0);
    f16*   ws_out1b = (f16*)  (ws + 24320000);
    f16*   ws_out2b = (f16*)  (ws + 37120000);
    f16*   ws_wtsd  = (f16*)  (ws + 76160000);
    f16*   ws_wt1   = (f16*)  (ws + 76313600);
    f16*   ws_wt2   = (f16*)  (ws + 76697600);
    f16*   ws_wt3   = (f16*)  (ws + 77427200);
    f16*   ws_wtl1  = (f16*)  (ws + 77792000);
    f16*   ws_wtl2  = (f16*)  (ws + 77955840);
    f16*   ws_wet   = (f16*)  (ws + 78021376);
    int*   ws_cnts  = (int*)  (ws + 78040832);   // [20000]
    int*   ws_rptr  = (int*)  (ws + 78120832);   // [20001]
    int*   ws_shad  = (int*)  (ws + 78200848);   // [20001]
    int*   ws_bsum  = (int*)  (ws + 78280864);   // [79]
    float* ws_pool  = (float*)(ws + 78281248);   // [64,128]

    dim3 blk(256);

    // casts + zero-init (cnts, pooled)
    cast_all<<<(CAST_TOTAL + 255) / 256, blk, 0, stream>>>(
        x, W_src, W_dst, W1, W2, W3, L1, L2, W_edge,
        ws_xb, ws_wtsd, ws_wt1, ws_wt2, ws_wt3, ws_wtl1, ws_wtl2, ws_wet,
        ws_cnts, ws_pool);

    // h | xd  = x @ [W_src ; W_dst]   (h f16 s304; xd -> out0b f16 s320, pads 0)
    hgemm_n128<false, false, false, 2><<<dim3(5 * 313), blk, 0, stream>>>(
        ws_xb, ws_wtsd, nullptr, nullptr, nullptr, ws_h, ws_out0b,
        5, N_NODES, 600, 128, 304, 608);

    // CSR build + fused scatter/gather
    hist_kernel<<<512, blk, 0, stream>>>(eidx, ws_cnts);
    {
        int nb = (N_NODES + 255) / 256;   // 79
        scan_a<<<nb, blk, 0, stream>>>(ws_cnts, ws_rptr, ws_bsum);
        scan_b<<<nb, blk, 0, stream>>>(ws_rptr, ws_shad, ws_bsum);
    }
    scatter_gather<<<(N_EDGES + 255) / 256, blk, 0, stream>>>(
        ea, eidx, ws_shad, ws_eaf, ws_srcs);

    // fused MFMA aggregation (out0b = agg + xd, RMW)
    agg_mfma<<<N_NODES / NPB, dim3(320), 0, stream>>>(
        ws_h, ws_eaf, ws_srcs, ws_rptr, ws_wet, ws_out0b);

    // MLP + encoder chain (f16 MFMA, fp32 accum), XCD-chunked block order
    hgemm_n128<true, true, true, 1><<<dim3(5 * 313), blk, 0, stream>>>(
        ws_out0b, ws_wt1, b1, g1, be1, ws_b1b, nullptr,
        5, N_NODES, 600, 320, 608, 608);
    hgemm_n128<true, true, true, 1><<<dim3(5 * 313), blk, 0, stream>>>(
        ws_b1b, ws_wt2, b2, g2, be2, ws_b2b, nullptr,
        5, N_NODES, 600, 608, 608, 608);
    hgemm_n128<true, false, false, 1><<<dim3(3 * 313), blk, 0, stream>>>(
        ws_b2b, ws_wt3, b3, nullptr, nullptr, ws_out1b, nullptr,
        3, N_NODES, 300, 608, 320, 320);
    hgemm<true, true, false, 1><<<dim3(4 * 313), blk, 0, stream>>>(
        ws_out1b, ws_wtl1, bl1, nullptr, nullptr, ws_out2b, nullptr, nullptr,
        4, N_NODES, 256, 320, 256, 256);
    // gemm5: epilogue pools directly (atomicAdd into pooled[batch[row]])
    hgemm<true, false, false, 3><<<dim3(2 * 313), blk, 0, stream>>>(
        ws_out2b, ws_wtl2, bl2, nullptr, nullptr, nullptr, ws_pool, batch,
        2, N_NODES, 128, 256, 128, 128);

    // finalize: per-graph mean via binary search on sorted batch
    finalize_kernel<<<(N_GRAPH * DOUT_DIM + 255) / 256, blk, 0, stream>>>(
        ws_pool, batch, out);
}